// Round 20
// baseline (169.374 us; speedup 1.0000x reference)
//
#include <hip/hip_runtime.h>
#include <hip/hip_bf16.h>

// Problem constants
#define B_  4
#define T_  2048
#define DM  1024
#define NH  16
#define DH  64
#define BT_ (B_*T_)    // 8192
#define F3  (3*DM)     // 3072

typedef unsigned short u16;
typedef float  f32x4  __attribute__((ext_vector_type(4)));
typedef short  short8 __attribute__((ext_vector_type(8)));
typedef __bf16 bf16x8 __attribute__((ext_vector_type(8)));
typedef unsigned short u16x8 __attribute__((ext_vector_type(8)));

__device__ __forceinline__ u16 f2b(float f){
  __hip_bfloat16 h = __float2bfloat16(f);
  return *reinterpret_cast<u16*>(&h);
}

__device__ __forceinline__ f32x4 mfma16(short8 a, short8 b, f32x4 c){
  return __builtin_amdgcn_mfma_f32_16x16x32_bf16((bf16x8)a, (bf16x8)b, c, 0, 0, 0);
}

// async global->LDS, 16B per lane; lds dest must be wave-uniform base (+lane*16 implicit)
__device__ __forceinline__ void gll16(const void* g, void* l){
  __builtin_amdgcn_global_load_lds((const __attribute__((address_space(1))) unsigned int*)g,
                                   (__attribute__((address_space(3))) unsigned int*)l,
                                   16, 0, 0);
}

#define BARRIER  __builtin_amdgcn_s_barrier()
#define LGKM0    asm volatile("s_waitcnt lgkmcnt(0)" ::: "memory")

// ---------------- fused f32 -> bf16 convert for all 3 inputs ----------------
#define N8_X  (BT_*DM/8)   // 1048576
#define N8_WQ (F3*DM/8)    // 393216
#define N8_WO (DM*DM/8)    // 131072
__global__ __launch_bounds__(256) void k_f2b3(const float* __restrict__ ax,
                                              const float* __restrict__ aq,
                                              const float* __restrict__ ao,
                                              u16* __restrict__ ox,
                                              u16* __restrict__ oq,
                                              u16* __restrict__ oo){
  int i = blockIdx.x*256 + threadIdx.x;
  const float* src; u16* dst; int k;
  if (i < N8_X)              { src = ax; dst = ox; k = i; }
  else if (i < N8_X + N8_WQ) { src = aq; dst = oq; k = i - N8_X; }
  else                       { src = ao; dst = oo; k = i - (N8_X + N8_WQ); }
  const float4* p = reinterpret_cast<const float4*>(src) + (size_t)k*2;
  float4 a = p[0], b = p[1];
  u16x8 r;
  r[0]=f2b(a.x); r[1]=f2b(a.y); r[2]=f2b(a.z); r[3]=f2b(a.w);
  r[4]=f2b(b.x); r[5]=f2b(b.y); r[6]=f2b(b.z); r[7]=f2b(b.w);
  *(reinterpret_cast<u16x8*>(dst) + k) = r;
}

// ---------------- 128x256-tile 8-phase GEMM  C = A * B^T ----------------
template<typename OUT>
__global__ __launch_bounds__(512, 1) void k_gemm8p(const u16* __restrict__ A,
                                                   const u16* __restrict__ Bm,
                                                   OUT* __restrict__ C,
                                                   int M, int N, int K){
  __shared__ __attribute__((aligned(16))) char smem[98304];
  char* lA0 = smem;           char* lA1 = smem + 16384;
  char* lB0 = smem + 32768;   char* lB1 = smem + 65536;

  int nbn = N >> 8;
  int bid = (int)blockIdx.x;
  int wg = (bid & 7)*((int)gridDim.x >> 3) + (bid >> 3);  // XCD swizzle (grid%8==0)
  int bm = wg / nbn, bn = wg % nbn;

  int tid = threadIdx.x, wv = tid >> 6, l = tid & 63;
  int lane16 = l & 15, lg = l >> 4;
  int wm = wv >> 2, wn = wv & 3;
  int rl = l >> 3;
  int sc = ((l & 7) ^ rl) * 8;          // pre-swizzled source column (u16)

  const u16* Ag = A  + (size_t)(bm*128 + wv*8 + rl)*K + sc;
  const u16* Bg = Bm + (size_t)(bn*256 + wv*8 + rl)*K + sc;

  auto SGA = [&](char* lbase, int t){
    const u16* g = Ag + t*64;
    char* ld = lbase + wv*1024;
    gll16(g, ld);
    gll16(g + (size_t)64*K, ld + 8192);
  };
  auto SGB = [&](char* lbase, int t){
    #pragma unroll
    for (int h = 0; h < 2; ++h){
      const u16* g = Bg + (size_t)h*128*K + t*64;
      char* ld = lbase + h*16384 + wv*1024;
      gll16(g, ld);
      gll16(g + (size_t)64*K, ld + 8192);
    }
  };
  auto RD = [&](const char* base, int row, int kk) -> short8 {
    return *(const short8*)(base + row*128 + (((kk*4 + lg) ^ (row & 7)) << 4));
  };

  f32x4 acc[4][4] = {};
  short8 am[4][2], bb[4][2];
  int ra = wm*64 + lane16;
  int rb = wn*64 + lane16;

  auto MFQ = [&](int n0){
    #pragma unroll
    for (int m = 0; m < 4; ++m)
      #pragma unroll
      for (int nn = 0; nn < 2; ++nn){
        int n = n0 + nn;
        acc[m][n] = mfma16(am[m][0], bb[n][0], acc[m][n]);
        acc[m][n] = mfma16(am[m][1], bb[n][1], acc[m][n]);
      }
  };

  // prologue: A0(0)[2] B0(0)[4] A1(1)[2] B1(1)[4]; wait oldest 6 (A0,B0)
  SGA(lA0, 0); SGB(lB0, 0); SGA(lA1, 1); SGB(lB1, 1);
  asm volatile("s_waitcnt vmcnt(6)" ::: "memory");
  BARRIER;

  int ni = K >> 7;
  #pragma unroll 1
  for (int i = 0; i < ni; ++i){
    bool last = (i == ni-1);
    int t0 = 2*i, t1 = 2*i + 1;
    // ---- ph1 ----
    #pragma unroll
    for (int m = 0; m < 4; ++m){ am[m][0]=RD(lA0, ra+m*16, 0); am[m][1]=RD(lA0, ra+m*16, 1); }
    #pragma unroll
    for (int n = 0; n < 2; ++n){ bb[n][0]=RD(lB0, rb+n*16, 0); bb[n][1]=RD(lB0, rb+n*16, 1); }
    if (i) SGB(lB1, t1);
    BARRIER; LGKM0;
    __builtin_amdgcn_s_setprio(1); MFQ(0); __builtin_amdgcn_s_setprio(0);
    BARRIER;
    // ---- ph2 ----
    #pragma unroll
    for (int n = 2; n < 4; ++n){ bb[n][0]=RD(lB0, rb+n*16, 0); bb[n][1]=RD(lB0, rb+n*16, 1); }
    if (!last) SGA(lA0, t0+2);
    if (last) asm volatile("s_waitcnt vmcnt(0)" ::: "memory");
    else      asm volatile("s_waitcnt vmcnt(2)" ::: "memory");
    BARRIER; LGKM0;
    __builtin_amdgcn_s_setprio(1); MFQ(2); __builtin_amdgcn_s_setprio(0);
    BARRIER;
    // ---- ph3 ----
    #pragma unroll
    for (int m = 0; m < 4; ++m){ am[m][0]=RD(lA1, ra+m*16, 0); am[m][1]=RD(lA1, ra+m*16, 1); }
    #pragma unroll
    for (int n = 0; n < 2; ++n){ bb[n][0]=RD(lB1, rb+n*16, 0); bb[n][1]=RD(lB1, rb+n*16, 1); }
    if (!last) SGB(lB0, t0+2);
    BARRIER; LGKM0;
    __builtin_amdgcn_s_setprio(1); MFQ(0); __builtin_amdgcn_s_setprio(0);
    BARRIER;
    // ---- ph4 ----
    #pragma unroll
    for (int n = 2; n < 4; ++n){ bb[n][0]=RD(lB1, rb+n*16, 0); bb[n][1]=RD(lB1, rb+n*16, 1); }
    if (!last){
      SGA(lA1, t1+2);
      asm volatile("s_waitcnt vmcnt(2)" ::: "memory");
    }
    BARRIER; LGKM0;
    __builtin_amdgcn_s_setprio(1); MFQ(2); __builtin_amdgcn_s_setprio(0);
    BARRIER;
  }

  #pragma unroll
  for (int m = 0; m < 4; ++m){
    #pragma unroll
    for (int n = 0; n < 4; ++n){
      #pragma unroll
      for (int r = 0; r < 4; ++r){
        int grow = bm*128 + wm*64 + m*16 + lg*4 + r;
        int gcol = bn*256 + wn*64 + n*16 + lane16;
        float v = acc[m][n][r];
        if constexpr (sizeof(OUT) == 2) C[(size_t)grow*N + gcol] = (OUT)f2b(v);
        else                            C[(size_t)grow*N + gcol] = v;
      }
    }
  }
}

// ---------------- Q|K GEMM: 256x256 8-phase + fused RoPE epilogue ----------------
__global__ __launch_bounds__(512, 1) void k_gemm_qk(const u16* __restrict__ A,
    const u16* __restrict__ Bm,
    const float* __restrict__ cosT, const float* __restrict__ sinT,
    u16* __restrict__ Qh, u16* __restrict__ Kh){
  __shared__ __attribute__((aligned(16))) char smem[131072];
  char* lA0 = smem;           char* lA1 = smem + 32768;
  char* lB0 = smem + 65536;   char* lB1 = smem + 98304;

  int bid = (int)blockIdx.x;
  int wg = (bid & 7)*32 + (bid >> 3);   // XCD swizzle (256 = 8*32)
  int bm = wg >> 3, bn = wg & 7;

  int tid = threadIdx.x, wv = tid >> 6, l = tid & 63;
  int lane16 = l & 15, lg = l >> 4;
  int wm = wv >> 2, wn = wv & 3;
  int rl = l >> 3;
  int sc = ((l & 7) ^ rl) * 8;          // pre-swizzled source column (u16)

  const u16* Ag = A  + (size_t)(bm*256 + wv*8 + rl)*DM + sc;
  const u16* Bg = Bm + (size_t)(bn*256 + wv*8 + rl)*DM + sc;

  auto SG = [&](const u16* gbase, char* lbase, int h, int t){
    const u16* g = gbase + (size_t)h*128*DM + t*64;
    char* ld = lbase + h*16384 + wv*1024;
    gll16(g, ld);
    gll16(g + (size_t)64*DM, ld + 8192);
  };
  auto RD = [&](const char* base, int row, int kk) -> short8 {
    return *(const short8*)(base + row*128 + (((kk*4 + lg) ^ (row & 7)) << 4));
  };

  f32x4 acc[8][4] = {};
  short8 am[4][2], bb[4][2];
  int ra = wm*128 + lane16;
  int rb = wn*64  + lane16;

  auto MF8 = [&](int mb, int n0){
    #pragma unroll
    for (int m = 0; m < 4; ++m)
      #pragma unroll
      for (int nn = 0; nn < 2; ++nn){
        int n = n0 + nn;
        acc[mb+m][n] = mfma16(am[m][0], bb[n][0], acc[mb+m][n]);
        acc[mb+m][n] = mfma16(am[m][1], bb[n][1], acc[mb+m][n]);
      }
  };

  // prologue
  SG(Bg,lB0,0,0); SG(Bg,lB0,1,0); SG(Ag,lA0,0,0); SG(Ag,lA0,1,0);
  SG(Bg,lB1,0,1); SG(Bg,lB1,1,1);
  asm volatile("s_waitcnt vmcnt(4)" ::: "memory");
  BARRIER;

  #pragma unroll 1
  for (int i = 0; i < 8; ++i){
    bool last = (i == 7);
    int t1 = 2*i + 1;
    // ---- phase 1 ----
    #pragma unroll
    for (int m = 0; m < 4; ++m){ am[m][0]=RD(lA0, ra+m*16, 0); am[m][1]=RD(lA0, ra+m*16, 1); }
    #pragma unroll
    for (int n = 0; n < 2; ++n){ bb[n][0]=RD(lB0, rb+n*16, 0); bb[n][1]=RD(lB0, rb+n*16, 1); }
    SG(Ag, lA1, 0, t1);
    BARRIER; LGKM0;
    __builtin_amdgcn_s_setprio(1); MF8(0,0); __builtin_amdgcn_s_setprio(0);
    BARRIER;
    // ---- phase 2 ----
    #pragma unroll
    for (int n = 2; n < 4; ++n){ bb[n][0]=RD(lB0, rb+n*16, 0); bb[n][1]=RD(lB0, rb+n*16, 1); }
    SG(Ag, lA1, 1, t1);
    BARRIER; LGKM0;
    __builtin_amdgcn_s_setprio(1); MF8(0,2); __builtin_amdgcn_s_setprio(0);
    BARRIER;
    // ---- phase 3 ----
    #pragma unroll
    for (int m = 0; m < 4; ++m){ am[m][0]=RD(lA0, ra+64+m*16, 0); am[m][1]=RD(lA0, ra+64+m*16, 1); }
    if (!last) SG(Bg, lB0, 0, 2*i+2);
    BARRIER; LGKM0;
    __builtin_amdgcn_s_setprio(1); MF8(4,0); __builtin_amdgcn_s_setprio(0);
    BARRIER;
    // ---- phase 4 ----
    if (!last) SG(Bg, lB0, 1, 2*i+2);
    if (last) asm volatile("s_waitcnt vmcnt(0)" ::: "memory");
    else      asm volatile("s_waitcnt vmcnt(4)" ::: "memory");
    BARRIER;
    __builtin_amdgcn_s_setprio(1); MF8(4,2); __builtin_amdgcn_s_setprio(0);
    BARRIER;
    // ---- phase 5 ----
    #pragma unroll
    for (int m = 0; m < 4; ++m){ am[m][0]=RD(lA1, ra+m*16, 0); am[m][1]=RD(lA1, ra+m*16, 1); }
    #pragma unroll
    for (int n = 0; n < 2; ++n){ bb[n][0]=RD(lB1, rb+n*16, 0); bb[n][1]=RD(lB1, rb+n*16, 1); }
    if (!last) SG(Ag, lA0, 0, 2*i+2);
    BARRIER; LGKM0;
    __builtin_amdgcn_s_setprio(1); MF8(0,0); __builtin_amdgcn_s_setprio(0);
    BARRIER;
    // ---- phase 6 ----
    #pragma unroll
    for (int n = 2; n < 4; ++n){ bb[n][0]=RD(lB1, rb+n*16, 0); bb[n][1]=RD(lB1, rb+n*16, 1); }
    if (!last) SG(Ag, lA0, 1, 2*i+2);
    BARRIER; LGKM0;
    __builtin_amdgcn_s_setprio(1); MF8(0,2); __builtin_amdgcn_s_setprio(0);
    BARRIER;
    // ---- phase 7 ----
    #pragma unroll
    for (int m = 0; m < 4; ++m){ am[m][0]=RD(lA1, ra+64+m*16, 0); am[m][1]=RD(lA1, ra+64+m*16, 1); }
    if (!last) SG(Bg, lB1, 0, 2*i+3);
    BARRIER; LGKM0;
    __builtin_amdgcn_s_setprio(1); MF8(4,0); __builtin_amdgcn_s_setprio(0);
    BARRIER;
    // ---- phase 8 ----
    if (!last){
      SG(Bg, lB1, 1, 2*i+3);
      asm volatile("s_waitcnt vmcnt(4)" ::: "memory");
    }
    BARRIER;
    __builtin_amdgcn_s_setprio(1); MF8(4,2); __builtin_amdgcn_s_setprio(0);
    BARRIER;
  }

  // ---------------- RoPE epilogue ----------------
  int sect = bn >> 2;                 // 0=q, 1=k
  int b2  = (bm*256) >> 11;
  int ttb = (bm*256) & 2047;
  u16* dst = sect ? Kh : Qh;
  float scq = sect ? 1.0f : 0.18033688011f;     // (1/8)*log2(e) folded into Q
  int h = (bn & 3)*4 + wn;
  size_t hrow = (size_t)(b2*NH + h)*T_;
  #pragma unroll
  for (int m = 0; m < 8; ++m){
    #pragma unroll
    for (int r = 0; r < 4; ++r){
      int t = ttb + wm*128 + m*16 + lg*4 + r;
      const float* cp = cosT + (size_t)t*64;
      const float* sp = sinT + (size_t)t*64;
      float c0 = cp[lane16],      s0 = sp[lane16];
      float c1 = cp[16 + lane16], s1 = sp[16 + lane16];
      float a0 = acc[m][0][r], a1 = acc[m][1][r];
      float a2 = acc[m][2][r], a3 = acc[m][3][r];
      size_t base = (hrow + t)*64;
      dst[base + lane16]      = f2b((a0*c0 - a2*s0)*scq);
      dst[base + 16 + lane16] = f2b((a1*c1 - a3*s1)*scq);
      dst[base + 32 + lane16] = f2b((a2*c0 + a0*s0)*scq);
      dst[base + 48 + lane16] = f2b((a3*c1 + a1*s1)*scq);
    }
  }
}

// ---------------- causal flash attention: (q-half x kv-half) wave split ----------
// R20: R15's merged pair {A=31-p, B=p} with the 4 waves split 2x2 over
// (q-half qsel, kv-half kvh). Wave computes its 32 q-rows x its 32 kv-rows for
// both tiles -> per-wave LDS reads drop 16 -> 8 ds_read_b128/iter (LDS port is
// the measured ~80% resource). V kv-half reads are WHOLE 16B chunks
// (chunk = kvh*4+lg), so the swizzle stays intact (R14's b64 mistake avoided).
// Cross-wave o/lsum reduction happens ONCE per block via a 32KB LDS exchange
// (not per-iter trees -- R14's other mistake avoided). All per-tile state in
// named, constant-indexed variables (R16-18 scratch lesson).
// launch_bounds(256,3): VGPR cap 170, est ~155 -- check VGPR_Count/WRITE_SIZE.
__global__ __launch_bounds__(256, 3) void k_attn(const u16* __restrict__ Qh,
    const u16* __restrict__ Kh, const u16* __restrict__ Vt, u16* __restrict__ AO){
  __shared__ __attribute__((aligned(16))) char smem[32768];   // lK[2] | lV[2]
  char* lK0 = smem;             char* lK1 = smem + 8192;
  char* lV0 = smem + 16384;     char* lV1 = smem + 24576;

  // bid bits: [2:0]=bh_lo (XCD), [5:3]=bh_hi, [9:6]=pair index p
  int bid = (int)blockIdx.x;
  int p = bid >> 6;
  int bh = ((bid >> 3) & 7) * 8 + (bid & 7);
  int b = bh >> 4, h = bh & 15;
  int tid = threadIdx.x, wv = tid >> 6, l = tid & 63;
  int lane16 = l & 15, lg = l >> 4;
  int qsel = wv & 1;            // q-half of each tile (rows qsel*32 .. +32)
  int kvh  = wv >> 1;           // kv-half of each tile (rows kvh*32 .. +32)

  const u16* Kb = Kh + (size_t)bh*T_*64;
  const u16* Vb = Vt + (size_t)h*64*BT_ + (size_t)b*T_;   // d-row stride = BT_

  int rl = l >> 3;
  int sc = ((l&7) ^ rl) * 8;

  auto STAGE = [&](int tile, int bufi){
    char* kd = (bufi ? lK1 : lK0) + wv*1024;
    char* vd = (bufi ? lV1 : lV0) + wv*1024;
    const u16* kg = Kb + (size_t)(tile*64 + wv*8 + rl)*64 + sc;
    const u16* vg = Vb + (size_t)(wv*8 + rl)*BT_ + tile*64 + sc;
    gll16(kg, kd);
    gll16(vg, vd);
    gll16(kg + 32*64, kd + 4096);
    gll16(vg + (size_t)32*BT_, vd + 4096);
  };

  int qtA = 31 - p, qtB = p;
  int qA0 = qtA*64, qB0 = qtB*64;
  int nt = qtA + 1;

  // Q fragments: 2 q-groups (qsel*32 + {0,16}) x 2 tiles, registers only
  short8 bqA0[2], bqA1[2], bqB0[2], bqB1[2];
  {
    const u16* q_;
    q_ = Qh + ((size_t)bh*T_ + qA0 + qsel*32 +  0 + lane16)*64 + lg*8;
    bqA0[0] = *(const short8*)q_;  bqA0[1] = *(const short8*)(q_ + 32);
    q_ = Qh + ((size_t)bh*T_ + qA0 + qsel*32 + 16 + lane16)*64 + lg*8;
    bqA1[0] = *(const short8*)q_;  bqA1[1] = *(const short8*)(q_ + 32);
    q_ = Qh + ((size_t)bh*T_ + qB0 + qsel*32 +  0 + lane16)*64 + lg*8;
    bqB0[0] = *(const short8*)q_;  bqB0[1] = *(const short8*)(q_ + 32);
    q_ = Qh + ((size_t)bh*T_ + qB0 + qsel*32 + 16 + lane16)*64 + lg*8;
    bqB1[0] = *(const short8*)q_;  bqB1[1] = *(const short8*)(q_ + 32);
  }

  f32x4 oA0[4] = {}, oA1[4] = {}, oB0[4] = {}, oB1[4] = {};   // [dn]
  float lsA0 = 0.f, lsA1 = 0.f, lsB0 = 0.f, lsB1 = 0.f;
  union U4 { unsigned u[4]; short8 v; };

// softmax(+diag mask)+pack for one (tile,qg): S = f32x4[2] (kv slices of this
// wave's half). Produces PK = A-fragment P[q=lane16][k = local 0..31].
#define SMPACK(S, LS, PK, QTV, QGOFF) do{                                      \
    if (it == (QTV)){                                                          \
      int q_abs = (QTV)*64 + qsel*32 + (QGOFF) + lane16;                       \
      _Pragma("unroll") for (int s_ = 0; s_ < 2; ++s_)                         \
        _Pragma("unroll") for (int r = 0; r < 4; ++r){                         \
          int key = kv0 + kvh*32 + s_*16 + lg*4 + r;                           \
          if (key > q_abs) S[s_][r] = -1e30f;                                  \
        }                                                                      \
    }                                                                          \
    { float rs_ = 0.f;                                                         \
      _Pragma("unroll") for (int s_ = 0; s_ < 2; ++s_)                         \
        _Pragma("unroll") for (int r = 0; r < 4; ++r){                         \
          float pe_ = __builtin_amdgcn_exp2f(S[s_][r]);                        \
          S[s_][r] = pe_; rs_ += pe_;                                          \
        }                                                                      \
      LS += rs_; }                                                             \
    { unsigned d0_[2], d1_[2];                                                 \
      asm("v_cvt_pk_bf16_f32 %0, %1, %2" : "=v"(d0_[0]) : "v"(S[0][0]), "v"(S[0][1])); \
      asm("v_cvt_pk_bf16_f32 %0, %1, %2" : "=v"(d0_[1]) : "v"(S[0][2]), "v"(S[0][3])); \
      asm("v_cvt_pk_bf16_f32 %0, %1, %2" : "=v"(d1_[0]) : "v"(S[1][0]), "v"(S[1][1])); \
      asm("v_cvt_pk_bf16_f32 %0, %1, %2" : "=v"(d1_[1]) : "v"(S[1][2]), "v"(S[1][3])); \
      _Pragma("unroll") for (int hh = 0; hh < 2; ++hh){                        \
        unsigned Aw_ = d0_[hh], Bw_ = d1_[hh];                                 \
        asm("v_permlane32_swap_b32 %0, %1" : "+v"(Aw_), "+v"(Bw_));            \
        asm("v_permlane16_swap_b32 %0, %1" : "+v"(Aw_), "+v"(Bw_));            \
        (PK).u[hh] = Aw_; (PK).u[2+hh] = Bw_;                                  \
      } }                                                                      \
  }while(0)

  STAGE(0, 0);

  for (int it = 0; it < nt; ++it){
    int cur = it & 1;
    asm volatile("s_waitcnt vmcnt(0)" ::: "memory");
    __builtin_amdgcn_s_barrier();
    if (it + 1 < nt) STAGE(it + 1, cur ^ 1);

    const char* Kc = cur ? lK1 : lK0;
    const char* Vc = cur ? lV1 : lV0;
    int kv0 = it*64;
    bool bact = (it <= qtB);           // wave-uniform

    // K fragments for this wave's kv-half: 2 slices x 2 k-chunks = 4 b128
    short8 ak[2][2];
    #pragma unroll
    for (int s_ = 0; s_ < 2; ++s_){
      int row = kvh*32 + s_*16 + lane16;
      ak[s_][0] = *(const short8*)(Kc + row*128 + (((lg    ) ^ (row&7))<<4));
      ak[s_][1] = *(const short8*)(Kc + row*128 + (((4 + lg) ^ (row&7))<<4));
    }

    // QK^T: s[qg][slice] = S^T[kv-local][q=lane16] for both tiles
    f32x4 sA0[2], sA1[2], sB0[2], sB1[2];
    __builtin_amdgcn_s_setprio(1);
    #pragma unroll
    for (int s_ = 0; s_ < 2; ++s_){
      f32x4 z;
      z = f32x4{};
      z = mfma16(ak[s_][0], bqA0[0], z);
      z = mfma16(ak[s_][1], bqA0[1], z);
      sA0[s_] = z;
      z = f32x4{};
      z = mfma16(ak[s_][0], bqA1[0], z);
      z = mfma16(ak[s_][1], bqA1[1], z);
      sA1[s_] = z;
      if (bact){
        z = f32x4{};
        z = mfma16(ak[s_][0], bqB0[0], z);
        z = mfma16(ak[s_][1], bqB0[1], z);
        sB0[s_] = z;
        z = f32x4{};
        z = mfma16(ak[s_][0], bqB1[0], z);
        z = mfma16(ak[s_][1], bqB1[1], z);
        sB1[s_] = z;
      }
    }
    __builtin_amdgcn_s_setprio(0);

    // softmax + pack (shift-free exp2; distinct-operand permlane)
    U4 pkA0, pkA1, pkB0, pkB1;
    SMPACK(sA0, lsA0, pkA0, qtA,  0);
    SMPACK(sA1, lsA1, pkA1, qtA, 16);
    if (bact){
      SMPACK(sB0, lsB0, pkB0, qtB,  0);
      SMPACK(sB1, lsB1, pkB1, qtB, 16);
    }

    // V fragments: d-rows, THIS wave's kv-half = whole 16B chunks (kvh*4+lg)
    short8 bv[4];
    #pragma unroll
    for (int dn = 0; dn < 4; ++dn){
      int row = dn*16 + lane16;
      bv[dn] = *(const short8*)(Vc + row*128 + (((kvh*4 + lg) ^ (row&7))<<4));
    }

    // PV: one K=32 MFMA per (tile, qg, dn) over this kv-half
    __builtin_amdgcn_s_setprio(1);
    #pragma unroll
    for (int dn = 0; dn < 4; ++dn){
      oA0[dn] = mfma16(pkA0.v, bv[dn], oA0[dn]);
      oA1[dn] = mfma16(pkA1.v, bv[dn], oA1[dn]);
      if (bact){
        oB0[dn] = mfma16(pkB0.v, bv[dn], oB0[dn]);
        oB1[dn] = mfma16(pkB1.v, bv[dn], oB1[dn]);
      }
    }
    __builtin_amdgcn_s_setprio(0);
  }

  // ---- reduce over lg groups (kv slots within this wave) ----
  lsA0 += __shfl_xor(lsA0, 16, 64);  lsA0 += __shfl_xor(lsA0, 32, 64);
  lsA1 += __shfl_xor(lsA1, 16, 64);  lsA1 += __shfl_xor(lsA1, 32, 64);
  lsB0 += __shfl_xor(lsB0, 16, 64);  lsB0 += __shfl_xor(lsB0, 32, 64);
  lsB1 += __shfl_xor(lsB1, 16, 64);  lsB1 += __shfl_xor(lsB1, 32, 64);

  // ---- cross-wave (kv-half) reduction: waves 2,3 dump; 0,1 accumulate ----
  __syncthreads();   // all compute done; LDS buffers reusable
  if (kvh == 1){
    char* R = smem + (wv - 2)*16384;
    #pragma unroll
    for (int dn = 0; dn < 4; ++dn){
      *(f32x4*)(R + l*256 + (((dn     ) ^ (l&7))<<4)) = oA0[dn];
      *(f32x4*)(R + l*256 + (((dn +  4) ^ (l&7))<<4)) = oA1[dn];
      *(f32x4*)(R + l*256 + (((dn +  8) ^ (l&7))<<4)) = oB0[dn];
      *(f32x4*)(R + l*256 + (((dn + 12) ^ (l&7))<<4)) = oB1[dn];
    }
  }
  __syncthreads();
  if (kvh == 0){
    const char* R = smem + wv*16384;   // partner wave wv+2 wrote (wv+2-2)*16384
    #pragma unroll
    for (int dn = 0; dn < 4; ++dn){
      oA0[dn] += *(const f32x4*)(R + l*256 + (((dn     ) ^ (l&7))<<4));
      oA1[dn] += *(const f32x4*)(R + l*256 + (((dn +  4) ^ (l&7))<<4));
      oB0[dn] += *(const f32x4*)(R + l*256 + (((dn +  8) ^ (l&7))<<4));
      oB1[dn] += *(const f32x4*)(R + l*256 + (((dn + 12) ^ (l&7))<<4));
    }
  }
  __syncthreads();
  if (kvh == 1){
    f32x4 lv = {lsA0, lsA1, lsB0, lsB1};
    *(f32x4*)(smem + (wv - 2)*1024 + l*16) = lv;
  }
  __syncthreads();
  if (kvh == 0){
    f32x4 lv = *(const f32x4*)(smem + wv*1024 + l*16);
    lsA0 += lv[0]; lsA1 += lv[1]; lsB0 += lv[2]; lsB1 += lv[3];

// epilogue for one (tile,qg): q = QTV*64 + qsel*32 + QGOFF + lg*4 + r (D-row),
// d = dn*16 + lane16 (D-col). lsum lives at q=lane16 -> broadcast like R15.
#define EPIL(O, LS, QTV, QGOFF) do{                                            \
    float inv_ = 1.f / (LS);                                                   \
    float ivr_[4];                                                             \
    _Pragma("unroll") for (int r = 0; r < 4; ++r)                              \
      ivr_[r] = __shfl(inv_, (l & 48) | (lg*4 + r), 64);                       \
    _Pragma("unroll") for (int r = 0; r < 4; ++r){                             \
      int tt_ = (QTV)*64 + qsel*32 + (QGOFF) + lg*4 + r;                       \
      _Pragma("unroll") for (int dn = 0; dn < 4; ++dn)                         \
        AO[((size_t)(b*T_ + tt_))*DM + h*64 + dn*16 + lane16] = f2b(O[dn][r]*ivr_[r]); \
    }                                                                          \
  }while(0)

    EPIL(oA0, lsA0, qtA,  0);
    EPIL(oA1, lsA1, qtA, 16);
    EPIL(oB0, lsB0, qtB,  0);
    EPIL(oB1, lsB1, qtB, 16);
#undef EPIL
  }
#undef SMPACK
}

// ---------------- launch ----------------
extern "C" void kernel_launch(void* const* d_in, const int* in_sizes, int n_in,
                              void* d_out, int out_size, void* d_ws, size_t ws_size,
                              hipStream_t stream) {
  const float* x     = (const float*)d_in[0];
  const float* cosT  = (const float*)d_in[1];
  const float* sinT  = (const float*)d_in[2];
  const float* w_qkv = (const float*)d_in[3];
  const float* w_out = (const float*)d_in[4];
  float* out = (float*)d_out;

  char* ws = (char*)d_ws;
  u16* xb    = (u16*)(ws);                      // 16 MB  (8192x1024 bf16)
  u16* wqkvb = (u16*)(ws + 16777216);           // 6 MB   (3072x1024)
  u16* woutb = (u16*)(ws + 23068672);           // 2 MB   (1024x1024)
  u16* AO    = (u16*)(ws + 25165824);           // 16 MB  (8192x1024)
  u16* Kh    = (u16*)(ws + 41943040);           // 16 MB  [BH][T][64]
  u16* Vt    = (u16*)(ws + 58720256);           // 16 MB  [H][64][B*T]
  u16* Qh    = (u16*)(ws + 75497472);           // 16 MB  -> total 88 MB

  // 1) convert all inputs to bf16 (single fused launch)
  k_f2b3<<<(N8_X+N8_WQ+N8_WO)/256, 256, 0, stream>>>(x, w_qkv, w_out, xb, wqkvb, woutb);

  // 2a) Q|K GEMM (256^2 8-phase, 256 blocks = exactly 1 pass) + RoPE epilogue
  k_gemm_qk<<<256, 512, 0, stream>>>(xb, wqkvb, cosT, sinT, Qh, Kh);

  // 2b) V as transposed GEMM: Vt = Wv @ x^T (128x256 8-phase, 256 blocks = 1 pass)
  k_gemm8p<u16><<<256, 512, 0, stream>>>(wqkvb + (size_t)2*DM*DM, xb, Vt, DM, BT_, DM);

  // 3) causal flash attention (q-half x kv-half wave split, merged pairs)
  k_attn<<<1024, 256, 0, stream>>>(Qh, Kh, Vt, AO);

  // 4) out = AO @ w_out^T (128x256 8-phase, 256 blocks = 1 pass; f32 out)
  k_gemm8p<float><<<256, 512, 0, stream>>>(AO, woutb, out, BT_, DM, DM);
}

// Round 21
// 152.122 us; speedup vs baseline: 1.1134x; 1.1134x over previous
//
#include <hip/hip_runtime.h>
#include <hip/hip_bf16.h>

// Problem constants
#define B_  4
#define T_  2048
#define DM  1024
#define NH  16
#define DH  64
#define BT_ (B_*T_)    // 8192
#define F3  (3*DM)     // 3072

typedef unsigned short u16;
typedef float  f32x4  __attribute__((ext_vector_type(4)));
typedef short  short8 __attribute__((ext_vector_type(8)));
typedef __bf16 bf16x8 __attribute__((ext_vector_type(8)));
typedef unsigned short u16x8 __attribute__((ext_vector_type(8)));

__device__ __forceinline__ u16 f2b(float f){
  __hip_bfloat16 h = __float2bfloat16(f);
  return *reinterpret_cast<u16*>(&h);
}

__device__ __forceinline__ f32x4 mfma16(short8 a, short8 b, f32x4 c){
  return __builtin_amdgcn_mfma_f32_16x16x32_bf16((bf16x8)a, (bf16x8)b, c, 0, 0, 0);
}

// async global->LDS, 16B per lane; lds dest must be wave-uniform base (+lane*16 implicit)
__device__ __forceinline__ void gll16(const void* g, void* l){
  __builtin_amdgcn_global_load_lds((const __attribute__((address_space(1))) unsigned int*)g,
                                   (__attribute__((address_space(3))) unsigned int*)l,
                                   16, 0, 0);
}

#define BARRIER  __builtin_amdgcn_s_barrier()
#define LGKM0    asm volatile("s_waitcnt lgkmcnt(0)" ::: "memory")

// ---------------- fused f32 -> bf16 convert for all 3 inputs ----------------
#define N8_X  (BT_*DM/8)   // 1048576
#define N8_WQ (F3*DM/8)    // 393216
#define N8_WO (DM*DM/8)    // 131072
__global__ __launch_bounds__(256) void k_f2b3(const float* __restrict__ ax,
                                              const float* __restrict__ aq,
                                              const float* __restrict__ ao,
                                              u16* __restrict__ ox,
                                              u16* __restrict__ oq,
                                              u16* __restrict__ oo){
  int i = blockIdx.x*256 + threadIdx.x;
  const float* src; u16* dst; int k;
  if (i < N8_X)              { src = ax; dst = ox; k = i; }
  else if (i < N8_X + N8_WQ) { src = aq; dst = oq; k = i - N8_X; }
  else                       { src = ao; dst = oo; k = i - (N8_X + N8_WQ); }
  const float4* p = reinterpret_cast<const float4*>(src) + (size_t)k*2;
  float4 a = p[0], b = p[1];
  u16x8 r;
  r[0]=f2b(a.x); r[1]=f2b(a.y); r[2]=f2b(a.z); r[3]=f2b(a.w);
  r[4]=f2b(b.x); r[5]=f2b(b.y); r[6]=f2b(b.z); r[7]=f2b(b.w);
  *(reinterpret_cast<u16x8*>(dst) + k) = r;
}

// ---------------- 128x256-tile 8-phase GEMM  C = A * B^T ----------------
// 512 threads = 8 waves (2M x 4N), per-wave 64x64 out = acc[4][4]. BK=64.
// Buffers: A0/A1 16KB, B0/B1 32KB (96KB total). 4 phases per 2 K-tiles,
// 16 MFMA per phase; counted vmcnt(2) at ph2/ph4; last iter vmcnt(0).
template<typename OUT>
__global__ __launch_bounds__(512, 1) void k_gemm8p(const u16* __restrict__ A,
                                                   const u16* __restrict__ Bm,
                                                   OUT* __restrict__ C,
                                                   int M, int N, int K){
  __shared__ __attribute__((aligned(16))) char smem[98304];
  char* lA0 = smem;           char* lA1 = smem + 16384;
  char* lB0 = smem + 32768;   char* lB1 = smem + 65536;

  int nbn = N >> 8;
  int bid = (int)blockIdx.x;
  int wg = (bid & 7)*((int)gridDim.x >> 3) + (bid >> 3);  // XCD swizzle (grid%8==0)
  int bm = wg / nbn, bn = wg % nbn;

  int tid = threadIdx.x, wv = tid >> 6, l = tid & 63;
  int lane16 = l & 15, lg = l >> 4;
  int wm = wv >> 2, wn = wv & 3;
  int rl = l >> 3;
  int sc = ((l & 7) ^ rl) * 8;          // pre-swizzled source column (u16)

  const u16* Ag = A  + (size_t)(bm*128 + wv*8 + rl)*K + sc;
  const u16* Bg = Bm + (size_t)(bn*256 + wv*8 + rl)*K + sc;

  auto SGA = [&](char* lbase, int t){
    const u16* g = Ag + t*64;
    char* ld = lbase + wv*1024;
    gll16(g, ld);
    gll16(g + (size_t)64*K, ld + 8192);
  };
  auto SGB = [&](char* lbase, int t){
    #pragma unroll
    for (int h = 0; h < 2; ++h){
      const u16* g = Bg + (size_t)h*128*K + t*64;
      char* ld = lbase + h*16384 + wv*1024;
      gll16(g, ld);
      gll16(g + (size_t)64*K, ld + 8192);
    }
  };
  auto RD = [&](const char* base, int row, int kk) -> short8 {
    return *(const short8*)(base + row*128 + (((kk*4 + lg) ^ (row & 7)) << 4));
  };

  f32x4 acc[4][4] = {};
  short8 am[4][2], bb[4][2];
  int ra = wm*64 + lane16;
  int rb = wn*64 + lane16;

  auto MFQ = [&](int n0){
    #pragma unroll
    for (int m = 0; m < 4; ++m)
      #pragma unroll
      for (int nn = 0; nn < 2; ++nn){
        int n = n0 + nn;
        acc[m][n] = mfma16(am[m][0], bb[n][0], acc[m][n]);
        acc[m][n] = mfma16(am[m][1], bb[n][1], acc[m][n]);
      }
  };

  // prologue: A0(0)[2] B0(0)[4] A1(1)[2] B1(1)[4]; wait oldest 6 (A0,B0)
  SGA(lA0, 0); SGB(lB0, 0); SGA(lA1, 1); SGB(lB1, 1);
  asm volatile("s_waitcnt vmcnt(6)" ::: "memory");
  BARRIER;

  int ni = K >> 7;
  #pragma unroll 1
  for (int i = 0; i < ni; ++i){
    bool last = (i == ni-1);
    int t0 = 2*i, t1 = 2*i + 1;
    // ---- ph1 ----
    #pragma unroll
    for (int m = 0; m < 4; ++m){ am[m][0]=RD(lA0, ra+m*16, 0); am[m][1]=RD(lA0, ra+m*16, 1); }
    #pragma unroll
    for (int n = 0; n < 2; ++n){ bb[n][0]=RD(lB0, rb+n*16, 0); bb[n][1]=RD(lB0, rb+n*16, 1); }
    if (i) SGB(lB1, t1);
    BARRIER; LGKM0;
    __builtin_amdgcn_s_setprio(1); MFQ(0); __builtin_amdgcn_s_setprio(0);
    BARRIER;
    // ---- ph2 ----
    #pragma unroll
    for (int n = 2; n < 4; ++n){ bb[n][0]=RD(lB0, rb+n*16, 0); bb[n][1]=RD(lB0, rb+n*16, 1); }
    if (!last) SGA(lA0, t0+2);
    if (last) asm volatile("s_waitcnt vmcnt(0)" ::: "memory");
    else      asm volatile("s_waitcnt vmcnt(2)" ::: "memory");
    BARRIER; LGKM0;
    __builtin_amdgcn_s_setprio(1); MFQ(2); __builtin_amdgcn_s_setprio(0);
    BARRIER;
    // ---- ph3 ----
    #pragma unroll
    for (int m = 0; m < 4; ++m){ am[m][0]=RD(lA1, ra+m*16, 0); am[m][1]=RD(lA1, ra+m*16, 1); }
    #pragma unroll
    for (int n = 0; n < 2; ++n){ bb[n][0]=RD(lB1, rb+n*16, 0); bb[n][1]=RD(lB1, rb+n*16, 1); }
    if (!last) SGB(lB0, t0+2);
    BARRIER; LGKM0;
    __builtin_amdgcn_s_setprio(1); MFQ(0); __builtin_amdgcn_s_setprio(0);
    BARRIER;
    // ---- ph4 ----
    #pragma unroll
    for (int n = 2; n < 4; ++n){ bb[n][0]=RD(lB1, rb+n*16, 0); bb[n][1]=RD(lB1, rb+n*16, 1); }
    if (!last){
      SGA(lA1, t1+2);
      asm volatile("s_waitcnt vmcnt(2)" ::: "memory");
    }
    BARRIER; LGKM0;
    __builtin_amdgcn_s_setprio(1); MFQ(2); __builtin_amdgcn_s_setprio(0);
    BARRIER;
  }

  #pragma unroll
  for (int m = 0; m < 4; ++m){
    #pragma unroll
    for (int n = 0; n < 4; ++n){
      #pragma unroll
      for (int r = 0; r < 4; ++r){
        int grow = bm*128 + wm*64 + m*16 + lg*4 + r;
        int gcol = bn*256 + wn*64 + n*16 + lane16;
        float v = acc[m][n][r];
        if constexpr (sizeof(OUT) == 2) C[(size_t)grow*N + gcol] = (OUT)f2b(v);
        else                            C[(size_t)grow*N + gcol] = v;
      }
    }
  }
}

// ---------------- Q|K GEMM: 256x256 8-phase + fused RoPE epilogue ----------------
__global__ __launch_bounds__(512, 1) void k_gemm_qk(const u16* __restrict__ A,
    const u16* __restrict__ Bm,
    const float* __restrict__ cosT, const float* __restrict__ sinT,
    u16* __restrict__ Qh, u16* __restrict__ Kh){
  __shared__ __attribute__((aligned(16))) char smem[131072];
  char* lA0 = smem;           char* lA1 = smem + 32768;
  char* lB0 = smem + 65536;   char* lB1 = smem + 98304;

  int bid = (int)blockIdx.x;
  int wg = (bid & 7)*32 + (bid >> 3);   // XCD swizzle (256 = 8*32)
  int bm = wg >> 3, bn = wg & 7;

  int tid = threadIdx.x, wv = tid >> 6, l = tid & 63;
  int lane16 = l & 15, lg = l >> 4;
  int wm = wv >> 2, wn = wv & 3;
  int rl = l >> 3;
  int sc = ((l & 7) ^ rl) * 8;          // pre-swizzled source column (u16)

  const u16* Ag = A  + (size_t)(bm*256 + wv*8 + rl)*DM + sc;
  const u16* Bg = Bm + (size_t)(bn*256 + wv*8 + rl)*DM + sc;

  auto SG = [&](const u16* gbase, char* lbase, int h, int t){
    const u16* g = gbase + (size_t)h*128*DM + t*64;
    char* ld = lbase + h*16384 + wv*1024;
    gll16(g, ld);
    gll16(g + (size_t)64*DM, ld + 8192);
  };
  auto RD = [&](const char* base, int row, int kk) -> short8 {
    return *(const short8*)(base + row*128 + (((kk*4 + lg) ^ (row & 7)) << 4));
  };

  f32x4 acc[8][4] = {};
  short8 am[4][2], bb[4][2];
  int ra = wm*128 + lane16;
  int rb = wn*64  + lane16;

  auto MF8 = [&](int mb, int n0){
    #pragma unroll
    for (int m = 0; m < 4; ++m)
      #pragma unroll
      for (int nn = 0; nn < 2; ++nn){
        int n = n0 + nn;
        acc[mb+m][n] = mfma16(am[m][0], bb[n][0], acc[mb+m][n]);
        acc[mb+m][n] = mfma16(am[m][1], bb[n][1], acc[mb+m][n]);
      }
  };

  // prologue
  SG(Bg,lB0,0,0); SG(Bg,lB0,1,0); SG(Ag,lA0,0,0); SG(Ag,lA0,1,0);
  SG(Bg,lB1,0,1); SG(Bg,lB1,1,1);
  asm volatile("s_waitcnt vmcnt(4)" ::: "memory");
  BARRIER;

  #pragma unroll 1
  for (int i = 0; i < 8; ++i){
    bool last = (i == 7);
    int t1 = 2*i + 1;
    // ---- phase 1 ----
    #pragma unroll
    for (int m = 0; m < 4; ++m){ am[m][0]=RD(lA0, ra+m*16, 0); am[m][1]=RD(lA0, ra+m*16, 1); }
    #pragma unroll
    for (int n = 0; n < 2; ++n){ bb[n][0]=RD(lB0, rb+n*16, 0); bb[n][1]=RD(lB0, rb+n*16, 1); }
    SG(Ag, lA1, 0, t1);
    BARRIER; LGKM0;
    __builtin_amdgcn_s_setprio(1); MF8(0,0); __builtin_amdgcn_s_setprio(0);
    BARRIER;
    // ---- phase 2 ----
    #pragma unroll
    for (int n = 2; n < 4; ++n){ bb[n][0]=RD(lB0, rb+n*16, 0); bb[n][1]=RD(lB0, rb+n*16, 1); }
    SG(Ag, lA1, 1, t1);
    BARRIER; LGKM0;
    __builtin_amdgcn_s_setprio(1); MF8(0,2); __builtin_amdgcn_s_setprio(0);
    BARRIER;
    // ---- phase 3 ----
    #pragma unroll
    for (int m = 0; m < 4; ++m){ am[m][0]=RD(lA0, ra+64+m*16, 0); am[m][1]=RD(lA0, ra+64+m*16, 1); }
    if (!last) SG(Bg, lB0, 0, 2*i+2);
    BARRIER; LGKM0;
    __builtin_amdgcn_s_setprio(1); MF8(4,0); __builtin_amdgcn_s_setprio(0);
    BARRIER;
    // ---- phase 4 ----
    if (!last) SG(Bg, lB0, 1, 2*i+2);
    if (last) asm volatile("s_waitcnt vmcnt(0)" ::: "memory");
    else      asm volatile("s_waitcnt vmcnt(4)" ::: "memory");
    BARRIER;
    __builtin_amdgcn_s_setprio(1); MF8(4,2); __builtin_amdgcn_s_setprio(0);
    BARRIER;
    // ---- phase 5 ----
    #pragma unroll
    for (int m = 0; m < 4; ++m){ am[m][0]=RD(lA1, ra+m*16, 0); am[m][1]=RD(lA1, ra+m*16, 1); }
    #pragma unroll
    for (int n = 0; n < 2; ++n){ bb[n][0]=RD(lB1, rb+n*16, 0); bb[n][1]=RD(lB1, rb+n*16, 1); }
    if (!last) SG(Ag, lA0, 0, 2*i+2);
    BARRIER; LGKM0;
    __builtin_amdgcn_s_setprio(1); MF8(0,0); __builtin_amdgcn_s_setprio(0);
    BARRIER;
    // ---- phase 6 ----
    #pragma unroll
    for (int n = 2; n < 4; ++n){ bb[n][0]=RD(lB1, rb+n*16, 0); bb[n][1]=RD(lB1, rb+n*16, 1); }
    if (!last) SG(Ag, lA0, 1, 2*i+2);
    BARRIER; LGKM0;
    __builtin_amdgcn_s_setprio(1); MF8(0,2); __builtin_amdgcn_s_setprio(0);
    BARRIER;
    // ---- phase 7 ----
    #pragma unroll
    for (int m = 0; m < 4; ++m){ am[m][0]=RD(lA1, ra+64+m*16, 0); am[m][1]=RD(lA1, ra+64+m*16, 1); }
    if (!last) SG(Bg, lB1, 0, 2*i+3);
    BARRIER; LGKM0;
    __builtin_amdgcn_s_setprio(1); MF8(4,0); __builtin_amdgcn_s_setprio(0);
    BARRIER;
    // ---- phase 8 ----
    if (!last){
      SG(Bg, lB1, 1, 2*i+3);
      asm volatile("s_waitcnt vmcnt(4)" ::: "memory");
    }
    BARRIER;
    __builtin_amdgcn_s_setprio(1); MF8(4,2); __builtin_amdgcn_s_setprio(0);
    BARRIER;
  }

  // ---------------- RoPE epilogue ----------------
  int sect = bn >> 2;                 // 0=q, 1=k
  int b2  = (bm*256) >> 11;
  int ttb = (bm*256) & 2047;
  u16* dst = sect ? Kh : Qh;
  float scq = sect ? 1.0f : 0.18033688011f;     // (1/8)*log2(e) folded into Q
  int h = (bn & 3)*4 + wn;
  size_t hrow = (size_t)(b2*NH + h)*T_;
  #pragma unroll
  for (int m = 0; m < 8; ++m){
    #pragma unroll
    for (int r = 0; r < 4; ++r){
      int t = ttb + wm*128 + m*16 + lg*4 + r;
      const float* cp = cosT + (size_t)t*64;
      const float* sp = sinT + (size_t)t*64;
      float c0 = cp[lane16],      s0 = sp[lane16];
      float c1 = cp[16 + lane16], s1 = sp[16 + lane16];
      float a0 = acc[m][0][r], a1 = acc[m][1][r];
      float a2 = acc[m][2][r], a3 = acc[m][3][r];
      size_t base = (hrow + t)*64;
      dst[base + lane16]      = f2b((a0*c0 - a2*s0)*scq);
      dst[base + 16 + lane16] = f2b((a1*c1 - a3*s1)*scq);
      dst[base + 32 + lane16] = f2b((a2*c0 + a0*s0)*scq);
      dst[base + 48 + lane16] = f2b((a3*c1 + a1*s1)*scq);
    }
  }
}

// ---------------- causal flash attention: merged q-tile pairs (R15-proven) ----
// Two paired q-tiles {A=31-p, B=p} merged into ONE kv loop: B's kv range is a
// strict prefix of A's, so each KV tile is staged AND LDS-read once per pair --
// K fragments (ak) and V fragments (bv) shared; only Q-side registers differ.
// Shift-free exp2 softmax (log2e/8 folded into Q upstream); in-register P via
// cvt_pk + permlane swaps (distinct-value operands only!).
// [Session ledger: R12 V-direct-from-L2 -82% (16 lines/instr); R14 kv-split
//  -33% (b64 broke swizzle + per-iter reduce trees); R16/R17/R18/R20 deeper
//  merges/splits all hit the same hipcc regalloc wall (caps ~84 VGPR, spills
//  to scratch, WRITE_SIZE 44-162MB). R15 = practical optimum: VGPR 64, 52us.]
__global__ __launch_bounds__(256, 4) void k_attn(const u16* __restrict__ Qh,
    const u16* __restrict__ Kh, const u16* __restrict__ Vt, u16* __restrict__ AO){
  __shared__ __attribute__((aligned(16))) u16 lK[2][64*64];
  __shared__ __attribute__((aligned(16))) u16 lV[2][64*64];

  // bid bits: [2:0]=bh_lo (XCD), [5:3]=bh_hi, [9:6]=pair index p
  int bid = (int)blockIdx.x;
  int p = bid >> 6;
  int bh = ((bid >> 3) & 7) * 8 + (bid & 7);
  int b = bh >> 4, h = bh & 15;
  int tid = threadIdx.x, wv = tid >> 6, l = tid & 63;
  int lane16 = l & 15, lg = l >> 4;

  const u16* Kb = Kh + (size_t)bh*T_*64;
  const u16* Vb = Vt + (size_t)h*64*BT_ + (size_t)b*T_;   // d-row stride = BT_

  int rl = l >> 3;
  int sc = ((l&7) ^ rl) * 8;

  auto STAGE = [&](int tile, int bufi){
    char* kd = (char*)lK[bufi] + wv*1024;
    char* vd = (char*)lV[bufi] + wv*1024;
    const u16* kg = Kb + (size_t)(tile*64 + wv*8 + rl)*64 + sc;
    const u16* vg = Vb + (size_t)(wv*8 + rl)*BT_ + tile*64 + sc;
    gll16(kg, kd);
    gll16(vg, vd);
    gll16(kg + 32*64, kd + 4096);
    gll16(vg + (size_t)32*BT_, vd + 4096);
  };

  int qtA = 31 - p, qtB = p;
  int qA0 = qtA*64, qB0 = qtB*64;
  int nt = qtA + 1;

  // Q fragments for both tiles (B-operand of swapped QK^T), registers only
  short8 bqA[2], bqB[2];
  {
    const u16* qa = Qh + ((size_t)bh*T_ + qA0 + wv*16 + lane16)*64 + lg*8;
    bqA[0] = *(const short8*)qa;  bqA[1] = *(const short8*)(qa + 32);
    const u16* qb = Qh + ((size_t)bh*T_ + qB0 + wv*16 + lane16)*64 + lg*8;
    bqB[0] = *(const short8*)qb;  bqB[1] = *(const short8*)(qb + 32);
  }

  f32x4 oA[4] = {}, oB[4] = {};
  float lsA = 0.f, lsB = 0.f;

  STAGE(0, 0);

  for (int it = 0; it < nt; ++it){
    int cur = it & 1;
    asm volatile("s_waitcnt vmcnt(0)" ::: "memory");
    __builtin_amdgcn_s_barrier();
    if (it + 1 < nt) STAGE(it + 1, cur ^ 1);

    const char* Kc = (const char*)lK[cur];
    const char* Vc = (const char*)lV[cur];
    int kv0 = it*64;
    bool bact = (it <= qtB);           // wave-uniform

    // shared K fragments; QK^T for A (always) and B (while active)
    f32x4 sA[4], sB[4];
    __builtin_amdgcn_s_setprio(1);
    #pragma unroll
    for (int n = 0; n < 4; ++n){
      int row = n*16 + lane16;
      short8 ak0 = *(const short8*)(Kc + row*128 + (((lg    ) ^ (row&7))<<4));
      short8 ak1 = *(const short8*)(Kc + row*128 + (((4 + lg) ^ (row&7))<<4));
      f32x4 z = {};
      z = mfma16(ak0, bqA[0], z);
      z = mfma16(ak1, bqA[1], z);
      sA[n] = z;
      if (bact){
        f32x4 y = {};
        y = mfma16(ak0, bqB[0], y);
        y = mfma16(ak1, bqB[1], y);
        sB[n] = y;
      }
    }
    __builtin_amdgcn_s_setprio(0);

    if (it == nt-1){   // A's diagonal tile
      int q_abs = qA0 + wv*16 + lane16;
      #pragma unroll
      for (int n = 0; n < 4; ++n)
        #pragma unroll
        for (int r = 0; r < 4; ++r){
          int key = kv0 + n*16 + lg*4 + r;
          if (key > q_abs) sA[n][r] = -1e30f;
        }
    }
    if (it == qtB){    // B's diagonal tile
      int q_abs = qB0 + wv*16 + lane16;
      #pragma unroll
      for (int n = 0; n < 4; ++n)
        #pragma unroll
        for (int r = 0; r < 4; ++r){
          int key = kv0 + n*16 + lg*4 + r;
          if (key > q_abs) sB[n][r] = -1e30f;
        }
    }

    // shift-free softmax numerators (s pre-scaled by log2e/8 upstream)
    {
      float rs = 0.f;
      #pragma unroll
      for (int n = 0; n < 4; ++n)
        #pragma unroll
        for (int r = 0; r < 4; ++r){
          float pe = __builtin_amdgcn_exp2f(sA[n][r]);
          sA[n][r] = pe; rs += pe;
        }
      lsA += rs;
    }
    if (bact){
      float rs = 0.f;
      #pragma unroll
      for (int n = 0; n < 4; ++n)
        #pragma unroll
        for (int r = 0; r < 4; ++r){
          float pe = __builtin_amdgcn_exp2f(sB[n][r]);
          sB[n][r] = pe; rs += pe;
        }
      lsB += rs;
    }

    // pack P to bf16 + permute into A-fragment layout (distinct-value operands!)
    union U4 { unsigned u[4]; short8 v; };
    U4 pkA0, pkA1, pkB0, pkB1;
    {
      unsigned d[4][2];
      #pragma unroll
      for (int n = 0; n < 4; ++n){
        asm("v_cvt_pk_bf16_f32 %0, %1, %2" : "=v"(d[n][0]) : "v"(sA[n][0]), "v"(sA[n][1]));
        asm("v_cvt_pk_bf16_f32 %0, %1, %2" : "=v"(d[n][1]) : "v"(sA[n][2]), "v"(sA[n][3]));
      }
      #pragma unroll
      for (int g = 0; g < 2; ++g)
        #pragma unroll
        for (int hh = 0; hh < 2; ++hh){
          unsigned A = d[2*g][hh], Bv = d[2*g+1][hh];
          asm("v_permlane32_swap_b32 %0, %1" : "+v"(A), "+v"(Bv));
          asm("v_permlane16_swap_b32 %0, %1" : "+v"(A), "+v"(Bv));
          if (g == 0){ pkA0.u[hh] = A; pkA0.u[2+hh] = Bv; }
          else       { pkA1.u[hh] = A; pkA1.u[2+hh] = Bv; }
        }
    }
    if (bact){
      unsigned d[4][2];
      #pragma unroll
      for (int n = 0; n < 4; ++n){
        asm("v_cvt_pk_bf16_f32 %0, %1, %2" : "=v"(d[n][0]) : "v"(sB[n][0]), "v"(sB[n][1]));
        asm("v_cvt_pk_bf16_f32 %0, %1, %2" : "=v"(d[n][1]) : "v"(sB[n][2]), "v"(sB[n][3]));
      }
      #pragma unroll
      for (int g = 0; g < 2; ++g)
        #pragma unroll
        for (int hh = 0; hh < 2; ++hh){
          unsigned A = d[2*g][hh], Bv = d[2*g+1][hh];
          asm("v_permlane32_swap_b32 %0, %1" : "+v"(A), "+v"(Bv));
          asm("v_permlane16_swap_b32 %0, %1" : "+v"(A), "+v"(Bv));
          if (g == 0){ pkB0.u[hh] = A; pkB0.u[2+hh] = Bv; }
          else       { pkB1.u[hh] = A; pkB1.u[2+hh] = Bv; }
        }
    }

    // PV: shared V fragments, both accumulators
    __builtin_amdgcn_s_setprio(1);
    #pragma unroll
    for (int dn = 0; dn < 4; ++dn){
      int row = dn*16 + lane16;
      short8 bv0 = *(const short8*)(Vc + row*128 + (((lg    ) ^ (row&7))<<4));
      short8 bv1 = *(const short8*)(Vc + row*128 + (((4 + lg) ^ (row&7))<<4));
      oA[dn] = mfma16(pkA0.v, bv0, oA[dn]);
      oA[dn] = mfma16(pkA1.v, bv1, oA[dn]);
      if (bact){
        oB[dn] = mfma16(pkB0.v, bv0, oB[dn]);
        oB[dn] = mfma16(pkB1.v, bv1, oB[dn]);
      }
    }
    __builtin_amdgcn_s_setprio(0);
  }

  // epilogue: normalize and write both q-tiles
  lsA += __shfl_xor(lsA, 16, 64);  lsA += __shfl_xor(lsA, 32, 64);
  lsB += __shfl_xor(lsB, 16, 64);  lsB += __shfl_xor(lsB, 32, 64);
  float invA = 1.f / lsA, invB = 1.f / lsB;
  float ivA[4], ivB[4];
  #pragma unroll
  for (int r = 0; r < 4; ++r){
    ivA[r] = __shfl(invA, (l & 48) | (lg*4 + r), 64);
    ivB[r] = __shfl(invB, (l & 48) | (lg*4 + r), 64);
  }
  #pragma unroll
  for (int r = 0; r < 4; ++r){
    int tA = qA0 + wv*16 + lg*4 + r;
    int tB = qB0 + wv*16 + lg*4 + r;
    #pragma unroll
    for (int dn = 0; dn < 4; ++dn){
      AO[((size_t)(b*T_ + tA))*DM + h*64 + dn*16 + lane16] = f2b(oA[dn][r]*ivA[r]);
      AO[((size_t)(b*T_ + tB))*DM + h*64 + dn*16 + lane16] = f2b(oB[dn][r]*ivB[r]);
    }
  }
}

// ---------------- launch ----------------
extern "C" void kernel_launch(void* const* d_in, const int* in_sizes, int n_in,
                              void* d_out, int out_size, void* d_ws, size_t ws_size,
                              hipStream_t stream) {
  const float* x     = (const float*)d_in[0];
  const float* cosT  = (const float*)d_in[1];
  const float* sinT  = (const float*)d_in[2];
  const float* w_qkv = (const float*)d_in[3];
  const float* w_out = (const float*)d_in[4];
  float* out = (float*)d_out;

  char* ws = (char*)d_ws;
  u16* xb    = (u16*)(ws);                      // 16 MB  (8192x1024 bf16)
  u16* wqkvb = (u16*)(ws + 16777216);           // 6 MB   (3072x1024)
  u16* woutb = (u16*)(ws + 23068672);           // 2 MB   (1024x1024)
  u16* AO    = (u16*)(ws + 25165824);           // 16 MB  (8192x1024)
  u16* Kh    = (u16*)(ws + 41943040);           // 16 MB  [BH][T][64]
  u16* Vt    = (u16*)(ws + 58720256);           // 16 MB  [H][64][B*T]
  u16* Qh    = (u16*)(ws + 75497472);           // 16 MB  -> total 88 MB

  // 1) convert all inputs to bf16 (single fused launch)
  k_f2b3<<<(N8_X+N8_WQ+N8_WO)/256, 256, 0, stream>>>(x, w_qkv, w_out, xb, wqkvb, woutb);

  // 2a) Q|K GEMM (256^2 8-phase, 256 blocks = exactly 1 pass) + RoPE epilogue
  k_gemm_qk<<<256, 512, 0, stream>>>(xb, wqkvb, cosT, sinT, Qh, Kh);

  // 2b) V as transposed GEMM: Vt = Wv @ x^T (128x256 8-phase, 256 blocks = 1 pass)
  k_gemm8p<u16><<<256, 512, 0, stream>>>(wqkvb + (size_t)2*DM*DM, xb, Vt, DM, BT_, DM);

  // 3) causal flash attention (merged q-tile pairs, 1024 blocks) -> AO bf16
  k_attn<<<1024, 256, 0, stream>>>(Qh, Kh, Vt, AO);

  // 4) out = AO @ w_out^T (128x256 8-phase, 256 blocks = 1 pass; f32 out)
  k_gemm8p<float><<<256, 512, 0, stream>>>(AO, woutb, out, BT_, DM, DM);
}